// Round 1
// baseline (207.536 us; speedup 1.0000x reference)
//
#include <hip/hip_runtime.h>
#include <cstdint>
#include <cstddef>

#define N_TOKENS 65536
#define DIM 64
#define K_CODES 1024
#define BT 64      // tokens per block
#define BJ 128     // codes per LDS chunk
#define NTHREADS 256

// out layout (floats): [0]=loss, [1..4194304]=quantized, [4194305]=perplexity,
// [4194306..4259841]=indices
#define OFF_Q 1
#define OFF_PERP 4194305
#define OFF_IDX 4194306

__device__ __forceinline__ float fmulr(float a, float b){ return __fmul_rn(a,b); }
__device__ __forceinline__ float faddr(float a, float b){ return __fadd_rn(a,b); }

// Emulate numpy's npyv/AVX512 pairwise sum of 64 fp32 squares:
// 4 vector accumulators of width 16: s[l] = (a[l]+a[l+16]) + (a[l+32]+a[l+48]);
// then hi/lo fold 16->8->4->2->1 (= _mm512_reduce_add_ps tree).
__device__ float sumsq64_np(const float* __restrict__ p) {
    float s[16];
    #pragma unroll
    for (int l = 0; l < 16; ++l) {
        float a0 = fmulr(p[l],      p[l]);
        float a1 = fmulr(p[l + 16], p[l + 16]);
        float a2 = fmulr(p[l + 32], p[l + 32]);
        float a3 = fmulr(p[l + 48], p[l + 48]);
        s[l] = faddr(faddr(a0, a1), faddr(a2, a3));
    }
    #pragma unroll
    for (int len = 8; len >= 1; len >>= 1) {
        #pragma unroll
        for (int l = 0; l < len; ++l)
            s[l] = faddr(s[l], s[l + len]);
    }
    return s[0];
}

__global__ __launch_bounds__(NTHREADS, 3)
void vq_main(const float* __restrict__ X, const float* __restrict__ W,
             float* __restrict__ out, double* __restrict__ loss_acc,
             int* __restrict__ counts) {
    __shared__ __align__(16) float xs[BT * DIM];    // swizzled [t][k]
    __shared__ __align__(16) float wsm[BJ * DIM];   // swizzled [jl][k]; aliased as u64 red[] later
    __shared__ float s1s[BT];
    __shared__ float s2s[BJ];
    __shared__ int   fidx[BT];
    __shared__ double lred[4];

    const int tid = threadIdx.x;
    const int r = tid & 15;   // token group: tokens 4r..4r+3
    const int c = tid >> 4;   // code group:  codes 8c..8c+7 (within chunk)
    const int t0 = blockIdx.x * BT;

    // ---- stage x tile (XOR-swizzled so k-loop b128 reads are conflict-free) ----
    {
        const float4* X4 = (const float4*)(X + (size_t)t0 * DIM);
        #pragma unroll
        for (int i = 0; i < 4; ++i) {
            int idx = tid + NTHREADS * i;        // 0..1023 float4s
            int t = idx >> 4, kb = idx & 15;
            float4 v = X4[idx];
            int base = t * DIM + ((kb ^ ((t >> 2) & 7)) << 2);
            *(float4*)&xs[base] = v;
        }
    }
    // ---- s1 per token, numpy reduction order (from global; rows are L1/L2 hot) ----
    if (tid < BT) s1s[tid] = sumsq64_np(X + (size_t)(t0 + tid) * DIM);

    float runVal[4]; int runIdx[4];
    #pragma unroll
    for (int i = 0; i < 4; ++i) { runVal[i] = 3.4e38f; runIdx[i] = 0; }

    for (int ch = 0; ch < K_CODES / BJ; ++ch) {
        __syncthreads();   // previous k-loop's LDS reads done
        // ---- stage w chunk (swizzled) ----
        {
            const float4* W4 = (const float4*)(W + (size_t)ch * BJ * DIM);
            #pragma unroll
            for (int i = 0; i < 8; ++i) {
                int idx = tid + NTHREADS * i;    // 0..2047 float4s
                int jl = idx >> 4, kb = idx & 15;
                float4 v = W4[idx];
                int base = jl * DIM + ((kb ^ ((jl >> 3) & 7)) << 2);
                *(float4*)&wsm[base] = v;
            }
        }
        if (tid < BJ) s2s[tid] = sumsq64_np(W + (size_t)(ch * BJ + tid) * DIM);
        __syncthreads();

        float acc[4][8];
        #pragma unroll
        for (int i = 0; i < 4; ++i)
            #pragma unroll
            for (int m = 0; m < 8; ++m) acc[i][m] = 0.0f;

        // ---- k-loop: sequential k order 0..63, FMA accumulation (matches BLAS sgemm) ----
        #pragma unroll
        for (int kb = 0; kb < 16; ++kb) {
            float4 xv[4], wv[8];
            #pragma unroll
            for (int i = 0; i < 4; ++i)
                xv[i] = *(const float4*)&xs[(4 * r + i) * DIM + ((kb ^ (r & 7)) << 2)];
            #pragma unroll
            for (int m = 0; m < 8; ++m)
                wv[m] = *(const float4*)&wsm[(8 * c + m) * DIM + ((kb ^ (c & 7)) << 2)];
            #pragma unroll
            for (int i = 0; i < 4; ++i) {
                #pragma unroll
                for (int m = 0; m < 8; ++m) {
                    acc[i][m] = __builtin_fmaf(xv[i].x, wv[m].x, acc[i][m]);
                    acc[i][m] = __builtin_fmaf(xv[i].y, wv[m].y, acc[i][m]);
                    acc[i][m] = __builtin_fmaf(xv[i].z, wv[m].z, acc[i][m]);
                    acc[i][m] = __builtin_fmaf(xv[i].w, wv[m].w, acc[i][m]);
                }
            }
        }

        // ---- distances (ref op order: (s1+s2) - 2P) + running argmin ----
        #pragma unroll
        for (int i = 0; i < 4; ++i) {
            float s1v = s1s[4 * r + i];
            #pragma unroll
            for (int m = 0; m < 8; ++m) {
                int jl = 8 * c + m;
                float t1 = faddr(s1v, s2s[jl]);
                float d  = faddr(t1, fmulr(-2.0f, acc[i][m]));
                if (d < runVal[i]) { runVal[i] = d; runIdx[i] = ch * BJ + jl; }
            }
        }
    }

    // ---- cross-thread argmin reduce: packed (f32bits<<32)|idx, u64 min ----
    __syncthreads();
    unsigned long long* red = (unsigned long long*)wsm;  // w chunk is dead now
    #pragma unroll
    for (int i = 0; i < 4; ++i) {
        unsigned long long pk =
            ((unsigned long long)__float_as_uint(runVal[i]) << 32) |
            (unsigned long long)(unsigned int)runIdx[i];
        red[(4 * r + i) * 16 + c] = pk;
    }
    __syncthreads();
    if (tid < BT) {
        unsigned long long best = red[tid * 16];
        #pragma unroll
        for (int cc = 1; cc < 16; ++cc) {
            unsigned long long v = red[tid * 16 + cc];
            best = (v < best) ? v : best;
        }
        int idx = (int)(best & 0xFFFFFFFFull);
        fidx[tid] = idx;
        atomicAdd(&counts[idx], 1);
        out[(size_t)OFF_IDX + t0 + tid] = (float)idx;
    }
    __syncthreads();

    // ---- quantized gather + loss partial (fp32 diffs, fp64 accumulate) ----
    double lsum = 0.0;
    float* outq = out + OFF_Q;
    #pragma unroll
    for (int i = 0; i < 16; ++i) {
        int e = tid + NTHREADS * i;          // 0..4095
        int t = e >> 6, dd = e & 63;
        int idx = fidx[t];
        float q = W[idx * DIM + dd];
        float x = X[(size_t)(t0 + t) * DIM + dd];
        outq[(size_t)(t0 + t) * DIM + dd] = q;
        float df = __fsub_rn(q, x);
        lsum += (double)fmulr(df, df);
    }
    #pragma unroll
    for (int off = 32; off >= 1; off >>= 1) lsum += __shfl_down(lsum, off);
    if ((tid & 63) == 0) lred[tid >> 6] = lsum;
    __syncthreads();
    if (tid == 0) {
        double tot = lred[0] + lred[1] + lred[2] + lred[3];
        atomicAdd(loss_acc, tot);
    }
}

__global__ void vq_final(const int* __restrict__ counts,
                         const double* __restrict__ loss_acc,
                         float* __restrict__ out) {
    __shared__ double hred[4];
    int tid = threadIdx.x;
    double h = 0.0;
    for (int j = tid; j < K_CODES; j += 256) {
        double p = (double)counts[j] / 65536.0;
        h += p * log(p + 1e-10);
    }
    #pragma unroll
    for (int off = 32; off >= 1; off >>= 1) h += __shfl_down(h, off);
    if ((tid & 63) == 0) hred[tid >> 6] = h;
    __syncthreads();
    if (tid == 0) {
        double H = hred[0] + hred[1] + hred[2] + hred[3];
        out[OFF_PERP] = (float)exp(-H);
        double ls = *loss_acc;
        float Lf = (float)(ls / 4194304.0);
        out[0] = faddr(Lf, fmulr(0.25f, Lf));   // q_latent + 0.25*e_latent (equal values)
    }
}

extern "C" void kernel_launch(void* const* d_in, const int* in_sizes, int n_in,
                              void* d_out, int out_size, void* d_ws, size_t ws_size,
                              hipStream_t stream) {
    const float* X = (const float*)d_in[0];   // inputs [65536 x 64]
    const float* W = (const float*)d_in[1];   // weight [1024 x 64]
    float* out = (float*)d_out;
    double* loss_acc = (double*)d_ws;                 // 8 bytes
    int* counts = (int*)((char*)d_ws + 8);            // 1024 ints

    hipMemsetAsync(d_ws, 0, 8 + K_CODES * sizeof(int), stream);
    vq_main<<<N_TOKENS / BT, NTHREADS, 0, stream>>>(X, W, out, loss_acc, counts);
    vq_final<<<1, 256, 0, stream>>>(counts, loss_acc, out);
}

// Round 2
// 177.327 us; speedup vs baseline: 1.1704x; 1.1704x over previous
//
#include <hip/hip_runtime.h>
#include <cstdint>
#include <cstddef>

#define N_TOKENS 65536
#define DIM 64
#define K_CODES 1024
#define NTH 256

// out layout (floats): [0]=loss, [1..4194304]=quantized, [4194305]=perplexity,
// [4194306..4259841]=indices
#define OFF_Q 1
#define OFF_PERP 4194305
#define OFF_IDX 4194306

// approx-vs-exact decision margin (worst-case error bound ~4.6e-5, 3.3x slack)
#define MARGIN 1.5e-4f

// ws byte offsets
#define WS_LOSS   0        // double
#define WS_FCNT   8        // int
#define WS_COUNTS 16       // int[1024]
#define WS_WHI    4112     // ushort[65536], 16B aligned, MFMA-swizzled
#define WS_WLO    135184   // ushort[65536]
#define WS_S2     266256   // float[1024]
#define WS_FLIST  270352   // ushort[65536]  -> total ~401 KB

typedef __attribute__((ext_vector_type(8))) short  s16x8;
typedef __attribute__((ext_vector_type(4))) float  f32x4;

__device__ __forceinline__ float fmulr(float a, float b){ return __fmul_rn(a,b); }
__device__ __forceinline__ float faddr(float a, float b){ return __fadd_rn(a,b); }

__device__ __forceinline__ unsigned short f2bf(float f) {
    unsigned u = __float_as_uint(f);
    unsigned r = u + 0x7fffu + ((u >> 16) & 1u);   // RNE
    return (unsigned short)(r >> 16);
}
__device__ __forceinline__ float bf2f(unsigned short h) {
    return __uint_as_float(((unsigned)h) << 16);
}
__device__ __forceinline__ unsigned keyf(float f) {  // monotone float->u32
    unsigned u = __float_as_uint(f);
    return u ^ ((u & 0x80000000u) ? 0xffffffffu : 0x80000000u);
}

// numpy (AVX512 pairwise) sum of 64 squares — validated bit-exact in round 1
__device__ float sumsq64_np(const float* __restrict__ p) {
    float s[16];
    #pragma unroll
    for (int l = 0; l < 16; ++l) {
        float a0 = fmulr(p[l],      p[l]);
        float a1 = fmulr(p[l + 16], p[l + 16]);
        float a2 = fmulr(p[l + 32], p[l + 32]);
        float a3 = fmulr(p[l + 48], p[l + 48]);
        s[l] = faddr(faddr(a0, a1), faddr(a2, a3));
    }
    #pragma unroll
    for (int len = 8; len >= 1; len >>= 1)
        #pragma unroll
        for (int l = 0; l < len; ++l)
            s[l] = faddr(s[l], s[l + len]);
    return s[0];
}

__device__ __forceinline__ void async_copy16(const void* g, void* l) {
    __builtin_amdgcn_global_load_lds(
        (const __attribute__((address_space(1))) void*)g,
        (__attribute__((address_space(3))) void*)l, 16, 0, 0);
}

// ---------------- prep: W -> swizzled bf16 hi/lo, exact s2, zero accumulators ----
__global__ void vq_prep(const float* __restrict__ W, unsigned short* __restrict__ Whi,
                        unsigned short* __restrict__ Wlo, float* __restrict__ s2g,
                        int* __restrict__ counts, int* __restrict__ gfcount,
                        double* __restrict__ loss_acc) {
    int gid = blockIdx.x * NTH + threadIdx.x;   // 64 blocks -> 16384 threads
    for (int e = gid; e < K_CODES * DIM; e += 16384) {
        float x = W[e];
        unsigned short hi = f2bf(x);
        unsigned short lo = f2bf(__fsub_rn(x, bf2f(hi)));
        int j = e >> 6, k = e & 63;
        int pos = j * 64 + (((k >> 3) ^ (j & 7)) << 3) + (k & 7);
        Whi[pos] = hi; Wlo[pos] = lo;
    }
    if (gid < K_CODES) { s2g[gid] = sumsq64_np(W + gid * 64); counts[gid] = 0; }
    if (gid == 0) { *loss_acc = 0.0; *gfcount = 0; }
}

// ---------------- main: MFMA approx distances + top2 + epilogue ------------------
__global__ __launch_bounds__(NTH, 3)
void vq_main(const float* __restrict__ X, const float* __restrict__ W,
             const unsigned short* __restrict__ WhiG, const unsigned short* __restrict__ WloG,
             const float* __restrict__ s2g, float* __restrict__ out,
             double* __restrict__ loss_acc, int* __restrict__ counts,
             int* __restrict__ gfcount, unsigned short* __restrict__ gflist) {
    __shared__ __align__(16) unsigned short xs_hi[64 * 64];
    __shared__ __align__(16) unsigned short xs_lo[64 * 64];
    __shared__ __align__(16) unsigned short ws_hi[128 * 64];
    __shared__ __align__(16) unsigned short ws_lo[128 * 64];
    __shared__ int fidx[64];
    __shared__ int flist[64];
    __shared__ int fcount, gbaseS;
    __shared__ double lred[4];

    const int tid  = threadIdx.x;
    const int lane = tid & 63, wave = tid >> 6;
    const int quad = lane >> 4, lrow = lane & 15;
    const int t0   = blockIdx.x * 64;

    if (tid == 0) fcount = 0;

    // stage X tile as swizzled bf16 hi/lo (512 groups of 8 floats)
    #pragma unroll
    for (int i = 0; i < 2; ++i) {
        int g = tid + NTH * i;
        int t = g >> 3, kb = g & 7;
        const float* src = X + (size_t)(t0 + t) * DIM + kb * 8;
        float v[8];
        *(f32x4*)v       = *(const f32x4*)src;
        *(f32x4*)(v + 4) = *(const f32x4*)(src + 4);
        unsigned short h[8], l[8];
        #pragma unroll
        for (int k = 0; k < 8; ++k) {
            h[k] = f2bf(v[k]);
            l[k] = f2bf(__fsub_rn(v[k], bf2f(h[k])));
        }
        int base = t * 64 + ((kb ^ (t & 7)) << 3);
        *(s16x8*)&xs_hi[base] = *(s16x8*)h;
        *(s16x8*)&xs_lo[base] = *(s16x8*)l;
    }
    __syncthreads();

    // A fragments (token side), fixed for whole kernel
    const int tf = wave * 16 + lrow;
    const int sA = tf & 7;
    s16x8 a_h0 = *(const s16x8*)&xs_hi[tf * 64 + (((0 + quad) ^ sA) << 3)];
    s16x8 a_h1 = *(const s16x8*)&xs_hi[tf * 64 + (((4 + quad) ^ sA) << 3)];
    s16x8 a_l0 = *(const s16x8*)&xs_lo[tf * 64 + (((0 + quad) ^ sA) << 3)];
    s16x8 a_l1 = *(const s16x8*)&xs_lo[tf * 64 + (((4 + quad) ^ sA) << 3)];

    float r1v[4], r2v[4]; int r1i[4];
    #pragma unroll
    for (int r = 0; r < 4; ++r) { r1v[r] = 3.4e38f; r2v[r] = 3.4e38f; r1i[r] = 0x7fffffff; }

    for (int ch = 0; ch < 8; ++ch) {
        __syncthreads();    // all waves done reading previous chunk
        {   // async stage W chunk (already bf16+swizzled in ws): straight 16KB copies
            const char* ghb = (const char*)WhiG + ch * 16384;
            const char* glb = (const char*)WloG + ch * 16384;
            char* lhb = (char*)ws_hi + wave * 1024;
            char* llb = (char*)ws_lo + wave * 1024;
            #pragma unroll
            for (int i = 0; i < 4; ++i) {
                int off = i * 4096 + tid * 16;
                async_copy16(ghb + off, lhb + i * 4096);
                async_copy16(glb + off, llb + i * 4096);
            }
        }
        __syncthreads();    // barrier drains vmcnt -> LDS ready

        #pragma unroll
        for (int g = 0; g < 2; ++g) {
            #pragma unroll
            for (int t4 = 0; t4 < 4; ++t4) {
                int jl = g * 64 + t4 * 16 + lrow;
                int sB = jl & 7;
                s16x8 b_h0 = *(const s16x8*)&ws_hi[jl * 64 + (((0 + quad) ^ sB) << 3)];
                s16x8 b_h1 = *(const s16x8*)&ws_hi[jl * 64 + (((4 + quad) ^ sB) << 3)];
                s16x8 b_l0 = *(const s16x8*)&ws_lo[jl * 64 + (((0 + quad) ^ sB) << 3)];
                s16x8 b_l1 = *(const s16x8*)&ws_lo[jl * 64 + (((4 + quad) ^ sB) << 3)];
                f32x4 acc = {0.f, 0.f, 0.f, 0.f};
                acc = __builtin_amdgcn_mfma_f32_16x16x32_bf16(a_h0, b_h0, acc, 0, 0, 0);
                acc = __builtin_amdgcn_mfma_f32_16x16x32_bf16(a_h1, b_h1, acc, 0, 0, 0);
                acc = __builtin_amdgcn_mfma_f32_16x16x32_bf16(a_h0, b_l0, acc, 0, 0, 0);
                acc = __builtin_amdgcn_mfma_f32_16x16x32_bf16(a_h1, b_l1, acc, 0, 0, 0);
                acc = __builtin_amdgcn_mfma_f32_16x16x32_bf16(a_l0, b_h0, acc, 0, 0, 0);
                acc = __builtin_amdgcn_mfma_f32_16x16x32_bf16(a_l1, b_h1, acc, 0, 0, 0);
                int jcode = ch * 128 + jl;
                float s2v = s2g[jcode];
                #pragma unroll
                for (int r = 0; r < 4; ++r) {   // rows = tokens wave*16+quad*4+r
                    float d = __builtin_fmaf(-2.0f, acc[r], s2v);
                    bool lt = d < r1v[r];       // strict: keeps earliest code on ties
                    float old1 = r1v[r];
                    float sec  = lt ? old1 : d;
                    r2v[r] = fminf(r2v[r], sec);
                    r1v[r] = lt ? d : r1v[r];
                    r1i[r] = lt ? jcode : r1i[r];
                }
            }
        }
    }

    // butterfly top-2 merge across the 16 lanes of each quad (codes disjoint per lane)
    #pragma unroll
    for (int m = 1; m <= 8; m <<= 1) {
        #pragma unroll
        for (int r = 0; r < 4; ++r) {
            float o1v = __shfl_xor(r1v[r], m, 64);
            int   o1i = __shfl_xor(r1i[r], m, 64);
            float o2v = __shfl_xor(r2v[r], m, 64);
            bool take = (o1v < r1v[r]) || (o1v == r1v[r] && o1i < r1i[r]);
            float loser = take ? r1v[r] : o1v;
            r2v[r] = fminf(fminf(r2v[r], o2v), loser);
            if (take) { r1v[r] = o1v; r1i[r] = o1i; }
        }
    }
    if (lrow == 0) {
        #pragma unroll
        for (int r = 0; r < 4; ++r) {
            int t = wave * 16 + quad * 4 + r;
            bool fb = (r2v[r] - r1v[r]) < MARGIN;
            fidx[t] = fb ? (r1i[r] | (int)0x80000000) : r1i[r];
            if (fb) { int p = atomicAdd(&fcount, 1); flist[p] = t; }
        }
    }
    __syncthreads();

    // epilogue for certain (non-fallback) tokens
    double lsum = 0.0;
    #pragma unroll
    for (int i = 0; i < 16; ++i) {
        int e = tid + NTH * i;
        int t = e >> 6, dd = e & 63;
        int iv = fidx[t];
        if (iv >= 0) {
            float q = W[iv * 64 + dd];
            float x = X[(size_t)(t0 + t) * 64 + dd];
            out[(size_t)OFF_Q + (size_t)(t0 + t) * 64 + dd] = q;
            float df = __fsub_rn(q, x);
            lsum += (double)fmulr(df, df);
        }
    }
    #pragma unroll
    for (int off = 32; off >= 1; off >>= 1) lsum += __shfl_down(lsum, off, 64);
    if (lane == 0) lred[wave] = lsum;
    if (tid < 64) {
        int iv = fidx[tid];
        if (iv >= 0) {
            atomicAdd(&counts[iv], 1);
            out[(size_t)OFF_IDX + t0 + tid] = (float)iv;
        }
    }
    if (tid == 0) gbaseS = atomicAdd(gfcount, fcount);
    __syncthreads();
    if (tid < fcount) gflist[gbaseS + tid] = (unsigned short)(t0 + flist[tid]);
    if (tid == 0) atomicAdd(loss_acc, lred[0] + lred[1] + lred[2] + lred[3]);
}

// ---------------- fallback: bit-exact (round-1 arithmetic) rescan ----------------
#define FGT 16
#define FBC 256

__global__ __launch_bounds__(NTH, 2)
void vq_fallback(const float* __restrict__ X, const float* __restrict__ W,
                 const float* __restrict__ s2g, const int* __restrict__ gfcount,
                 const unsigned short* __restrict__ gflist, float* __restrict__ out,
                 double* __restrict__ loss_acc, int* __restrict__ counts) {
    int count = *gfcount;
    int base = blockIdx.x * FGT;
    if (base >= count) return;
    int nt = min(FGT, count - base);

    __shared__ __align__(16) float xsf[FGT * 64];
    __shared__ __align__(16) float wsf[FBC * 64];
    __shared__ float s1f[FGT];
    __shared__ unsigned long long redf[FGT * 32];
    __shared__ int gidx[FGT];
    __shared__ double lredf[4];

    const int tid = threadIdx.x;
    const int lane = tid & 63, wave = tid >> 6;
    const int r = tid & 7, c = tid >> 3;          // r: token pair, c: 0..31 code octet

    if (tid < nt * 16) {
        int t = tid >> 4, kb4 = tid & 15;
        int tok = gflist[base + t];
        f32x4 v = *(const f32x4*)(X + (size_t)tok * 64 + kb4 * 4);
        *(f32x4*)&xsf[t * 64 + ((kb4 ^ (t & 7)) << 2)] = v;
    }
    if (tid < nt) s1f[tid] = sumsq64_np(X + (size_t)gflist[base + tid] * 64);

    unsigned long long best0 = ~0ULL, best1 = ~0ULL;
    const int ta = 2 * r, tb = 2 * r + 1;

    for (int ch = 0; ch < K_CODES / FBC; ++ch) {
        __syncthreads();
        #pragma unroll
        for (int i = 0; i < 16; ++i) {           // stage 256x64 fp32 W chunk
            int e = tid + NTH * i;
            int jl = e >> 4, kb4 = e & 15;
            f32x4 v = *(const f32x4*)(W + (size_t)(ch * FBC + jl) * 64 + kb4 * 4);
            *(f32x4*)&wsf[jl * 64 + ((kb4 ^ ((jl >> 3) & 7)) << 2)] = v;
        }
        __syncthreads();

        float acc[2][8];
        #pragma unroll
        for (int m = 0; m < 8; ++m) { acc[0][m] = 0.f; acc[1][m] = 0.f; }

        #pragma unroll
        for (int kb4 = 0; kb4 < 16; ++kb4) {     // exact sequential-k FMA chains
            f32x4 xa = *(const f32x4*)&xsf[ta * 64 + ((kb4 ^ (ta & 7)) << 2)];
            f32x4 xb = *(const f32x4*)&xsf[tb * 64 + ((kb4 ^ (tb & 7)) << 2)];
            #pragma unroll
            for (int m = 0; m < 8; ++m) {
                int jl = 8 * c + m;
                f32x4 wv = *(const f32x4*)&wsf[jl * 64 + ((kb4 ^ (c & 7)) << 2)];
                acc[0][m] = __builtin_fmaf(xa[0], wv[0], acc[0][m]);
                acc[0][m] = __builtin_fmaf(xa[1], wv[1], acc[0][m]);
                acc[0][m] = __builtin_fmaf(xa[2], wv[2], acc[0][m]);
                acc[0][m] = __builtin_fmaf(xa[3], wv[3], acc[0][m]);
                acc[1][m] = __builtin_fmaf(xb[0], wv[0], acc[1][m]);
                acc[1][m] = __builtin_fmaf(xb[1], wv[1], acc[1][m]);
                acc[1][m] = __builtin_fmaf(xb[2], wv[2], acc[1][m]);
                acc[1][m] = __builtin_fmaf(xb[3], wv[3], acc[1][m]);
            }
        }
        #pragma unroll
        for (int m = 0; m < 8; ++m) {
            int jcode = ch * FBC + 8 * c + m;
            float s2v = s2g[jcode];
            float d0 = faddr(faddr(s1f[ta], s2v), fmulr(-2.0f, acc[0][m]));
            float d1 = faddr(faddr(s1f[tb], s2v), fmulr(-2.0f, acc[1][m]));
            unsigned long long p0 = ((unsigned long long)keyf(d0) << 32) | (unsigned)jcode;
            unsigned long long p1 = ((unsigned long long)keyf(d1) << 32) | (unsigned)jcode;
            best0 = p0 < best0 ? p0 : best0;
            best1 = p1 < best1 ? p1 : best1;
        }
    }
    redf[ta * 32 + c] = best0;
    redf[tb * 32 + c] = best1;
    __syncthreads();
    if (tid < FGT) {
        unsigned long long b = redf[tid * 32];
        #pragma unroll
        for (int cc = 1; cc < 32; ++cc) {
            unsigned long long v = redf[tid * 32 + cc];
            b = v < b ? v : b;
        }
        int idx = (int)(b & 0xffffffffu);
        gidx[tid] = idx;
        if (tid < nt) {
            int tok = gflist[base + tid];
            out[(size_t)OFF_IDX + tok] = (float)idx;
            atomicAdd(&counts[idx], 1);
        }
    }
    __syncthreads();
    double lsum = 0.0;
    #pragma unroll
    for (int i = 0; i < 4; ++i) {
        int e = tid + NTH * i;
        int t = e >> 6, dd = e & 63;
        if (t < nt) {
            int tok = gflist[base + t];
            int idx = gidx[t];
            float q = W[idx * 64 + dd];
            float x = X[(size_t)tok * 64 + dd];
            out[(size_t)OFF_Q + (size_t)tok * 64 + dd] = q;
            float df = __fsub_rn(q, x);
            lsum += (double)fmulr(df, df);
        }
    }
    #pragma unroll
    for (int off = 32; off >= 1; off >>= 1) lsum += __shfl_down(lsum, off, 64);
    if (lane == 0) lredf[wave] = lsum;
    __syncthreads();
    if (tid == 0) atomicAdd(loss_acc, lredf[0] + lredf[1] + lredf[2] + lredf[3]);
}

// ---------------- final scalars --------------------------------------------------
__global__ void vq_final(const int* __restrict__ counts,
                         const double* __restrict__ loss_acc,
                         float* __restrict__ out) {
    __shared__ double hred[4];
    int tid = threadIdx.x;
    double h = 0.0;
    for (int j = tid; j < K_CODES; j += 256) {
        double p = (double)counts[j] / 65536.0;
        h += p * log(p + 1e-10);
    }
    #pragma unroll
    for (int off = 32; off >= 1; off >>= 1) h += __shfl_down(h, off, 64);
    if ((tid & 63) == 0) hred[tid >> 6] = h;
    __syncthreads();
    if (tid == 0) {
        double H = hred[0] + hred[1] + hred[2] + hred[3];
        out[OFF_PERP] = (float)exp(-H);
        double ls = *loss_acc;
        float Lf = (float)(ls / 4194304.0);
        out[0] = faddr(Lf, fmulr(0.25f, Lf));
    }
}

extern "C" void kernel_launch(void* const* d_in, const int* in_sizes, int n_in,
                              void* d_out, int out_size, void* d_ws, size_t ws_size,
                              hipStream_t stream) {
    const float* X = (const float*)d_in[0];
    const float* W = (const float*)d_in[1];
    float* out = (float*)d_out;
    char* ws = (char*)d_ws;
    double* loss_acc = (double*)(ws + WS_LOSS);
    int* gfcount = (int*)(ws + WS_FCNT);
    int* counts = (int*)(ws + WS_COUNTS);
    unsigned short* Whi = (unsigned short*)(ws + WS_WHI);
    unsigned short* Wlo = (unsigned short*)(ws + WS_WLO);
    float* s2g = (float*)(ws + WS_S2);
    unsigned short* gflist = (unsigned short*)(ws + WS_FLIST);

    vq_prep<<<64, NTH, 0, stream>>>(W, Whi, Wlo, s2g, counts, gfcount, loss_acc);
    vq_main<<<N_TOKENS / 64, NTH, 0, stream>>>(X, W, Whi, Wlo, s2g, out,
                                               loss_acc, counts, gfcount, gflist);
    vq_fallback<<<N_TOKENS / FGT, NTH, 0, stream>>>(X, W, s2g, gfcount, gflist,
                                                    out, loss_acc, counts);
    vq_final<<<1, NTH, 0, stream>>>(counts, loss_acc, out);
}

// Round 3
// 171.367 us; speedup vs baseline: 1.2111x; 1.0348x over previous
//
#include <hip/hip_runtime.h>
#include <cstdint>
#include <cstddef>

#define N_TOKENS 65536
#define DIM 64
#define K_CODES 1024
#define NTH 256
#define TPB 128                 // tokens per main block
#define NCH 16                  // chunks of 64 codes

// out layout (floats): [0]=loss, [1..4194304]=quantized, [4194305]=perplexity,
// [4194306..4259841]=indices
#define OFF_Q 1
#define OFF_PERP 4194305
#define OFF_IDX 4194306

// approx-vs-exact decision margin (worst-case error bound ~4.6e-5, 3.3x slack)
#define MARGIN 1.5e-4f

// ws byte offsets
#define WS_LOSS   0        // double
#define WS_FCNT   8        // int
#define WS_COUNTS 16       // int[1024]
#define WS_WHI    4112     // ushort[65536], 16B aligned, MFMA-swizzled
#define WS_WLO    135184   // ushort[65536]
#define WS_S2     266256   // float[1024]
#define WS_FLIST  270352   // ushort[65536]

typedef __attribute__((ext_vector_type(8))) short  s16x8;
typedef __attribute__((ext_vector_type(4))) float  f32x4;

__device__ __forceinline__ float fmulr(float a, float b){ return __fmul_rn(a,b); }
__device__ __forceinline__ float faddr(float a, float b){ return __fadd_rn(a,b); }

__device__ __forceinline__ unsigned short f2bf(float f) {
    unsigned u = __float_as_uint(f);
    unsigned r = u + 0x7fffu + ((u >> 16) & 1u);   // RNE
    return (unsigned short)(r >> 16);
}
__device__ __forceinline__ float bf2f(unsigned short h) {
    return __uint_as_float(((unsigned)h) << 16);
}

// numpy (AVX512 pairwise) sum of 64 squares — validated bit-exact in rounds 1-2
__device__ float sumsq64_np(const float* __restrict__ p) {
    float s[16];
    #pragma unroll
    for (int l = 0; l < 16; ++l) {
        float a0 = fmulr(p[l],      p[l]);
        float a1 = fmulr(p[l + 16], p[l + 16]);
        float a2 = fmulr(p[l + 32], p[l + 32]);
        float a3 = fmulr(p[l + 48], p[l + 48]);
        s[l] = faddr(faddr(a0, a1), faddr(a2, a3));
    }
    #pragma unroll
    for (int len = 8; len >= 1; len >>= 1)
        #pragma unroll
        for (int l = 0; l < len; ++l)
            s[l] = faddr(s[l], s[l + len]);
    return s[0];
}

__device__ __forceinline__ void async_copy16(const void* g, void* l) {
    __builtin_amdgcn_global_load_lds(
        (const __attribute__((address_space(1))) void*)g,
        (__attribute__((address_space(3))) void*)l, 16, 0, 0);
}

// ---------------- prep: W -> swizzled bf16 hi/lo, exact s2, zero accumulators ----
__global__ void vq_prep(const float* __restrict__ W, unsigned short* __restrict__ Whi,
                        unsigned short* __restrict__ Wlo, float* __restrict__ s2g,
                        int* __restrict__ counts, int* __restrict__ gfcount,
                        double* __restrict__ loss_acc) {
    int gid = blockIdx.x * NTH + threadIdx.x;   // 64 blocks -> 16384 threads
    for (int e = gid; e < K_CODES * DIM; e += 16384) {
        float x = W[e];
        unsigned short hi = f2bf(x);
        unsigned short lo = f2bf(__fsub_rn(x, bf2f(hi)));
        int j = e >> 6, k = e & 63;
        int pos = j * 64 + (((k >> 3) ^ (j & 7)) << 3) + (k & 7);
        Whi[pos] = hi; Wlo[pos] = lo;
    }
    if (gid < K_CODES) { s2g[gid] = sumsq64_np(W + gid * 64); counts[gid] = 0; }
    if (gid == 0) { *loss_acc = 0.0; *gfcount = 0; }
}

// ---------------- main: MFMA approx distances, dbuf prefetch, top2, epilogue -----
__global__ __launch_bounds__(NTH, 2)
void vq_main(const float* __restrict__ X, const float* __restrict__ W,
             const unsigned short* __restrict__ WhiG, const unsigned short* __restrict__ WloG,
             const float* __restrict__ s2g, float* __restrict__ out,
             double* __restrict__ loss_acc, int* __restrict__ counts,
             int* __restrict__ gfcount, unsigned short* __restrict__ gflist) {
    __shared__ __align__(16) unsigned short xs_hi[TPB * 64];
    __shared__ __align__(16) unsigned short xs_lo[TPB * 64];
    __shared__ __align__(16) unsigned short ws_hi[2][64 * 64];   // dbuf, 8KB each
    __shared__ __align__(16) unsigned short ws_lo[2][64 * 64];
    __shared__ __align__(16) float s2s[K_CODES];
    __shared__ int fidx[TPB];
    __shared__ int flist[TPB];
    __shared__ int fcount, gbaseS;
    __shared__ double lred[4];

    const int tid  = threadIdx.x;
    const int lane = tid & 63, wave = tid >> 6;
    const int quad = lane >> 4, lrow = lane & 15;
    const int t0   = blockIdx.x * TPB;

    if (tid == 0) fcount = 0;

    // prefetch chunk 0 first so it overlaps X staging
    {
        const char* gh = (const char*)WhiG;
        const char* gl = (const char*)WloG;
        char* lh = (char*)&ws_hi[0][0] + wave * 1024;
        char* ll = (char*)&ws_lo[0][0] + wave * 1024;
        #pragma unroll
        for (int i = 0; i < 2; ++i) {
            async_copy16(gh + i * 4096 + tid * 16, lh + i * 4096);
            async_copy16(gl + i * 4096 + tid * 16, ll + i * 4096);
        }
    }
    // stage s2 (4KB)
    *(f32x4*)&s2s[tid * 4] = *(const f32x4*)&s2g[tid * 4];
    // stage X tile as swizzled bf16 hi/lo (1024 groups of 8 floats)
    #pragma unroll
    for (int i = 0; i < 4; ++i) {
        int g = tid + NTH * i;
        int t = g >> 3, kb = g & 7;
        const float* src = X + (size_t)(t0 + t) * DIM + kb * 8;
        float v[8];
        *(f32x4*)v       = *(const f32x4*)src;
        *(f32x4*)(v + 4) = *(const f32x4*)(src + 4);
        unsigned short h[8], l[8];
        #pragma unroll
        for (int k = 0; k < 8; ++k) {
            h[k] = f2bf(v[k]);
            l[k] = f2bf(__fsub_rn(v[k], bf2f(h[k])));
        }
        int base = t * 64 + ((kb ^ (t & 7)) << 3);
        *(s16x8*)&xs_hi[base] = *(s16x8*)h;
        *(s16x8*)&xs_lo[base] = *(s16x8*)l;
    }
    __syncthreads();   // X/s2 staged (lgkm), chunk-0 prefetch drained (vmcnt)

    // A fragments in registers for the whole kernel: wave owns 32 tokens (2 row-tiles)
    s16x8 a_h0[2], a_h1[2], a_l0[2], a_l1[2];
    #pragma unroll
    for (int rt = 0; rt < 2; ++rt) {
        int tf = wave * 32 + rt * 16 + lrow;
        int sA = tf & 7;
        a_h0[rt] = *(const s16x8*)&xs_hi[tf * 64 + (((0 + quad) ^ sA) << 3)];
        a_h1[rt] = *(const s16x8*)&xs_hi[tf * 64 + (((4 + quad) ^ sA) << 3)];
        a_l0[rt] = *(const s16x8*)&xs_lo[tf * 64 + (((0 + quad) ^ sA) << 3)];
        a_l1[rt] = *(const s16x8*)&xs_lo[tf * 64 + (((4 + quad) ^ sA) << 3)];
    }

    float r1v[8], r2v[8]; int r1i[8];
    #pragma unroll
    for (int ri = 0; ri < 8; ++ri) { r1v[ri] = 3.4e38f; r2v[ri] = 3.4e38f; r1i[ri] = 0x7fffffff; }

    for (int ch = 0; ch < NCH; ++ch) {
        const int buf = ch & 1;
        if (ch < NCH - 1) {   // prefetch next chunk into other buffer (in flight all chunk)
            const char* gh = (const char*)WhiG + (ch + 1) * 8192;
            const char* gl = (const char*)WloG + (ch + 1) * 8192;
            char* lh = (char*)&ws_hi[buf ^ 1][0] + wave * 1024;
            char* ll = (char*)&ws_lo[buf ^ 1][0] + wave * 1024;
            #pragma unroll
            for (int i = 0; i < 2; ++i) {
                async_copy16(gh + i * 4096 + tid * 16, lh + i * 4096);
                async_copy16(gl + i * 4096 + tid * 16, ll + i * 4096);
            }
        }
        #pragma unroll
        for (int ct = 0; ct < 4; ++ct) {
            int lc = ct * 16 + lrow;          // local code 0..63 (this lane's C-column)
            int sB = lrow & 7;
            const unsigned short* bh = &ws_hi[buf][lc * 64];
            const unsigned short* bl = &ws_lo[buf][lc * 64];
            s16x8 b_h0 = *(const s16x8*)&bh[((0 + quad) ^ sB) << 3];
            s16x8 b_h1 = *(const s16x8*)&bh[((4 + quad) ^ sB) << 3];
            s16x8 b_l0 = *(const s16x8*)&bl[((0 + quad) ^ sB) << 3];
            s16x8 b_l1 = *(const s16x8*)&bl[((4 + quad) ^ sB) << 3];
            int jcode = ch * 64 + lc;
            float s2v = s2s[jcode];
            float ainit = fmulr(-0.5f, s2v);
            #pragma unroll
            for (int rt = 0; rt < 2; ++rt) {
                f32x4 acc = {ainit, ainit, ainit, ainit};   // fold s2: d = -2*acc
                acc = __builtin_amdgcn_mfma_f32_16x16x32_bf16(a_h0[rt], b_h0, acc, 0, 0, 0);
                acc = __builtin_amdgcn_mfma_f32_16x16x32_bf16(a_h1[rt], b_h1, acc, 0, 0, 0);
                acc = __builtin_amdgcn_mfma_f32_16x16x32_bf16(a_h0[rt], b_l0, acc, 0, 0, 0);
                acc = __builtin_amdgcn_mfma_f32_16x16x32_bf16(a_h1[rt], b_l1, acc, 0, 0, 0);
                acc = __builtin_amdgcn_mfma_f32_16x16x32_bf16(a_l0[rt], b_h0, acc, 0, 0, 0);
                acc = __builtin_amdgcn_mfma_f32_16x16x32_bf16(a_l1[rt], b_h1, acc, 0, 0, 0);
                #pragma unroll
                for (int r = 0; r < 4; ++r) {
                    float d = fmulr(-2.0f, acc[r]);
                    int ri = rt * 4 + r;
                    bool lt = d < r1v[ri];      // strict: keeps earliest code on ties
                    float sec = lt ? r1v[ri] : d;
                    r2v[ri] = fminf(r2v[ri], sec);
                    r1v[ri] = lt ? d : r1v[ri];
                    r1i[ri] = lt ? jcode : r1i[ri];
                }
            }
        }
        __syncthreads();   // drains next-chunk prefetch; protects buf reuse
    }

    // butterfly top-2 merge across the 16 lrow lanes (codes disjoint per lane)
    #pragma unroll
    for (int m = 1; m <= 8; m <<= 1) {
        #pragma unroll
        for (int ri = 0; ri < 8; ++ri) {
            float o1v = __shfl_xor(r1v[ri], m, 64);
            int   o1i = __shfl_xor(r1i[ri], m, 64);
            float o2v = __shfl_xor(r2v[ri], m, 64);
            bool take = (o1v < r1v[ri]) || (o1v == r1v[ri] && o1i < r1i[ri]);
            float loser = take ? r1v[ri] : o1v;
            r2v[ri] = fminf(fminf(r2v[ri], o2v), loser);
            if (take) { r1v[ri] = o1v; r1i[ri] = o1i; }
        }
    }
    if (lrow == 0) {
        #pragma unroll
        for (int ri = 0; ri < 8; ++ri) {
            int rt = ri >> 2, r = ri & 3;
            int t = wave * 32 + rt * 16 + quad * 4 + r;
            bool fb = (r2v[ri] - r1v[ri]) < MARGIN;
            fidx[t] = fb ? (r1i[ri] | (int)0x80000000) : r1i[ri];
            if (fb) { int p = atomicAdd(&fcount, 1); flist[p] = t; }
        }
    }
    __syncthreads();

    // epilogue for certain (non-fallback) tokens, float4-vectorized
    double lsum = 0.0;
    #pragma unroll
    for (int i = 0; i < 8; ++i) {
        int e4 = tid + NTH * i;              // 0..2047 float4 groups
        int t = e4 >> 4, d4 = (e4 & 15) * 4;
        int iv = fidx[t];
        if (iv >= 0) {
            f32x4 q = *(const f32x4*)&W[iv * 64 + d4];
            f32x4 x = *(const f32x4*)&X[(size_t)(t0 + t) * 64 + d4];
            *(f32x4*)&out[(size_t)OFF_Q + (size_t)(t0 + t) * 64 + d4] = q;
            #pragma unroll
            for (int c = 0; c < 4; ++c) {
                float df = __fsub_rn(q[c], x[c]);
                lsum += (double)fmulr(df, df);
            }
        }
    }
    #pragma unroll
    for (int off = 32; off >= 1; off >>= 1) lsum += __shfl_down(lsum, off, 64);
    if (lane == 0) lred[wave] = lsum;
    if (tid < TPB) {
        int iv = fidx[tid];
        if (iv >= 0) {
            atomicAdd(&counts[iv], 1);
            out[(size_t)OFF_IDX + t0 + tid] = (float)iv;
        }
    }
    if (tid == 0) gbaseS = atomicAdd(gfcount, fcount);
    __syncthreads();
    if (tid < fcount) gflist[gbaseS + tid] = (unsigned short)(t0 + flist[tid]);
    if (tid == 0) atomicAdd(loss_acc, lred[0] + lred[1] + lred[2] + lred[3]);
}

// ---------------- fallback: bit-exact (round-1 arithmetic) rescan, 64 tok/block --
__global__ __launch_bounds__(NTH, 3)
void vq_fallback(const float* __restrict__ X, const float* __restrict__ W,
                 const float* __restrict__ s2g, const int* __restrict__ gfcount,
                 const unsigned short* __restrict__ gflist, float* __restrict__ out,
                 double* __restrict__ loss_acc, int* __restrict__ counts) {
    int count = *gfcount;
    int base = blockIdx.x * 64;
    if (base >= count) return;
    int nt = min(64, count - base);

    __shared__ __align__(16) float xsf[64 * 64];     // 16KB
    __shared__ __align__(16) float wsf[128 * 64];    // 32KB; aliased as u64 red[] later
    __shared__ float s1f[64];
    __shared__ int gidx[64];
    __shared__ double lredf[4];

    const int tid = threadIdx.x;
    const int lane = tid & 63, wave = tid >> 6;
    const int r = tid & 15, c = tid >> 4;   // r: tokens 4r..4r+3, c: codes 8c..8c+7

    // stage X rows of the fallback tokens (padded with token gflist[base])
    #pragma unroll
    for (int i = 0; i < 4; ++i) {
        int idx = tid + NTH * i;            // 0..1023 float4 groups
        int t = idx >> 4, kb = idx & 15;
        int tok = gflist[base + (t < nt ? t : 0)];
        f32x4 v = *(const f32x4*)(X + (size_t)tok * 64 + kb * 4);
        *(f32x4*)&xsf[t * 64 + ((kb ^ ((t >> 2) & 7)) << 2)] = v;
    }
    if (tid < nt) s1f[tid] = sumsq64_np(X + (size_t)gflist[base + tid] * 64);

    float runVal[4]; int runIdx[4];
    #pragma unroll
    for (int i = 0; i < 4; ++i) { runVal[i] = 3.4e38f; runIdx[i] = 0; }

    for (int ch = 0; ch < 8; ++ch) {
        __syncthreads();
        #pragma unroll
        for (int i = 0; i < 8; ++i) {        // stage 128x64 fp32 W chunk, swizzled
            int idx = tid + NTH * i;
            int jl = idx >> 4, kb = idx & 15;
            f32x4 v = *(const f32x4*)(W + (size_t)(ch * 128 + jl) * 64 + kb * 4);
            *(f32x4*)&wsf[jl * 64 + ((kb ^ ((jl >> 3) & 7)) << 2)] = v;
        }
        __syncthreads();

        float acc[4][8];
        #pragma unroll
        for (int i = 0; i < 4; ++i)
            #pragma unroll
            for (int m = 0; m < 8; ++m) acc[i][m] = 0.0f;

        #pragma unroll
        for (int kb = 0; kb < 16; ++kb) {    // exact sequential-k FMA chains
            f32x4 xv[4], wv[8];
            #pragma unroll
            for (int i = 0; i < 4; ++i)
                xv[i] = *(const f32x4*)&xsf[(4 * r + i) * 64 + ((kb ^ (r & 7)) << 2)];
            #pragma unroll
            for (int m = 0; m < 8; ++m)
                wv[m] = *(const f32x4*)&wsf[(8 * c + m) * 64 + ((kb ^ (c & 7)) << 2)];
            #pragma unroll
            for (int i = 0; i < 4; ++i)
                #pragma unroll
                for (int m = 0; m < 8; ++m) {
                    acc[i][m] = __builtin_fmaf(xv[i][0], wv[m][0], acc[i][m]);
                    acc[i][m] = __builtin_fmaf(xv[i][1], wv[m][1], acc[i][m]);
                    acc[i][m] = __builtin_fmaf(xv[i][2], wv[m][2], acc[i][m]);
                    acc[i][m] = __builtin_fmaf(xv[i][3], wv[m][3], acc[i][m]);
                }
        }
        #pragma unroll
        for (int i = 0; i < 4; ++i) {
            float s1v = s1f[4 * r + i];
            #pragma unroll
            for (int m = 0; m < 8; ++m) {
                int jl = 8 * c + m;
                float d = faddr(faddr(s1v, s2g[ch * 128 + jl]), fmulr(-2.0f, acc[i][m]));
                if (d < runVal[i]) { runVal[i] = d; runIdx[i] = ch * 128 + jl; }
            }
        }
    }

    __syncthreads();
    unsigned long long* red = (unsigned long long*)wsf;   // w chunk dead now
    #pragma unroll
    for (int i = 0; i < 4; ++i) {
        unsigned long long pk =
            ((unsigned long long)__float_as_uint(runVal[i]) << 32) |
            (unsigned long long)(unsigned int)runIdx[i];   // d>0 always (s1 dominates)
        red[(4 * r + i) * 16 + c] = pk;
    }
    __syncthreads();
    if (tid < 64) {
        unsigned long long best = red[tid * 16];
        #pragma unroll
        for (int cc = 1; cc < 16; ++cc) {
            unsigned long long v = red[tid * 16 + cc];
            best = (v < best) ? v : best;
        }
        int idx = (int)(best & 0xffffffffu);
        gidx[tid] = idx;
        if (tid < nt) {
            int tok = gflist[base + tid];
            out[(size_t)OFF_IDX + tok] = (float)idx;
            atomicAdd(&counts[idx], 1);
        }
    }
    __syncthreads();
    double lsum = 0.0;
    #pragma unroll
    for (int i = 0; i < 4; ++i) {
        int e4 = tid + NTH * i;              // 0..1023 float4 groups
        int t = e4 >> 4, d4 = (e4 & 15) * 4;
        if (t < nt) {
            int tok = gflist[base + t];
            int idx = gidx[t];
            f32x4 q = *(const f32x4*)&W[idx * 64 + d4];
            f32x4 x = *(const f32x4*)&X[(size_t)tok * 64 + d4];
            *(f32x4*)&out[(size_t)OFF_Q + (size_t)tok * 64 + d4] = q;
            #pragma unroll
            for (int cc = 0; cc < 4; ++cc) {
                float df = __fsub_rn(q[cc], x[cc]);
                lsum += (double)fmulr(df, df);
            }
        }
    }
    #pragma unroll
    for (int off = 32; off >= 1; off >>= 1) lsum += __shfl_down(lsum, off, 64);
    if (lane == 0) lredf[wave] = lsum;
    __syncthreads();
    if (tid == 0) atomicAdd(loss_acc, lredf[0] + lredf[1] + lredf[2] + lredf[3]);
}

// ---------------- final scalars --------------------------------------------------
__global__ void vq_final(const int* __restrict__ counts,
                         const double* __restrict__ loss_acc,
                         float* __restrict__ out) {
    __shared__ double hred[4];
    int tid = threadIdx.x;
    double h = 0.0;
    for (int j = tid; j < K_CODES; j += 256) {
        double p = (double)counts[j] / 65536.0;
        h += p * log(p + 1e-10);
    }
    #pragma unroll
    for (int off = 32; off >= 1; off >>= 1) h += __shfl_down(h, off, 64);
    if ((tid & 63) == 0) hred[tid >> 6] = h;
    __syncthreads();
    if (tid == 0) {
        double H = hred[0] + hred[1] + hred[2] + hred[3];
        out[OFF_PERP] = (float)exp(-H);
        double ls = *loss_acc;
        float Lf = (float)(ls / 4194304.0);
        out[0] = faddr(Lf, fmulr(0.25f, Lf));
    }
}

extern "C" void kernel_launch(void* const* d_in, const int* in_sizes, int n_in,
                              void* d_out, int out_size, void* d_ws, size_t ws_size,
                              hipStream_t stream) {
    const float* X = (const float*)d_in[0];
    const float* W = (const float*)d_in[1];
    float* out = (float*)d_out;
    char* ws = (char*)d_ws;
    double* loss_acc = (double*)(ws + WS_LOSS);
    int* gfcount = (int*)(ws + WS_FCNT);
    int* counts = (int*)(ws + WS_COUNTS);
    unsigned short* Whi = (unsigned short*)(ws + WS_WHI);
    unsigned short* Wlo = (unsigned short*)(ws + WS_WLO);
    float* s2g = (float*)(ws + WS_S2);
    unsigned short* gflist = (unsigned short*)(ws + WS_FLIST);

    vq_prep<<<64, NTH, 0, stream>>>(W, Whi, Wlo, s2g, counts, gfcount, loss_acc);
    vq_main<<<N_TOKENS / TPB, NTH, 0, stream>>>(X, W, Whi, Wlo, s2g, out,
                                                loss_acc, counts, gfcount, gflist);
    vq_fallback<<<N_TOKENS / 64, NTH, 0, stream>>>(X, W, s2g, gfcount, gflist,
                                                   out, loss_acc, counts);
    vq_final<<<1, NTH, 0, stream>>>(counts, loss_acc, out);
}